// Round 2
// baseline (732.567 us; speedup 1.0000x reference)
//
#include <hip/hip_runtime.h>
#include <math.h>

// Problem constants (fixed by setup_inputs): B=4, H=W=896, n_h=n_w=64,
// GS=8, GL=8, LS=16, LL=8, NA=12, ALPHA=0.5
#define HWPIX 802816            // 896*896
#define OUT_IL 9633792          // offset of I_local  (4*3*896*896)
#define OUT_GG 19267584         // offset of G_global
#define OUT_GL 19292160         // offset of G_local
#define OUT_G  19390464         // offset of g

// workspace layout (float offsets)
#define WS_WT4  0               // combined weight, packed [k/4][o][4], 256x640
#define WS_BC   163840          // combined bias, 256
#define WS_POOL 164096          // pooled [b][c][cell], 4*256*256
#define WS_H    426240          // h vector, 4*256
#define WS_GSEM 427264          // g_sem_patch, 4*4096
#define WS_RG   443648          // global grid [b][y][x][z][c], 4*8*8*8*12
#define WS_RL   468224          // local grid  [b][y][x][z][c], 4*16*16*8*12
#define WS_W1T  566528          // guide_w1 transposed [k][hidden], 384*64

__device__ __forceinline__ float srgb_lin(float v) {
  return v > 0.04045f ? __powf((v + 0.055f) * (1.0f / 1.055f), 2.4f)
                      : v * (1.0f / 12.92f);
}
__device__ __forceinline__ float labf(float t) {
  return t > 0.008856f ? cbrtf(t) : 7.787f * t + (4.0f / 29.0f);
}

// ---------------------------------------------------------------------------
// K1: combined weight W[o][k] (k<256: fusion Wa; k>=256: Wb @ dino_proj_w)
// packed as Wt4[(k>>2)*256 + o][k&3]; plus bc[o] = fusion_b + Wb @ dino_b.
// block 641 transposes guide_w1 -> w1T[k*64+h].
__global__ __launch_bounds__(256) void k_prep(
    const float* __restrict__ fus_w, const float* __restrict__ fus_b,
    const float* __restrict__ dino_w, const float* __restrict__ dino_b,
    const float* __restrict__ gw1, float* __restrict__ Wt4,
    float* __restrict__ bc, float* __restrict__ w1T) {
  if (blockIdx.x == 641) {
    int t = threadIdx.x;
    for (int it = 0; it < 96; ++it) {
      int idx = it * 256 + t;       // idx = k*64 + h
      int h = idx & 63;
      int k = idx >> 6;
      w1T[idx] = gw1[h * 384 + k];
    }
    return;
  }
  if (blockIdx.x == 640) {
    int o = threadIdx.x;
    float acc = fus_b[o];
    for (int m = 0; m < 128; ++m) acc += fus_w[o * 384 + 256 + m] * dino_b[m];
    bc[o] = acc;
    return;
  }
  int idx = blockIdx.x * 256 + threadIdx.x;
  int o = idx / 640;
  int k = idx - o * 640;
  float val;
  if (k < 256) {
    val = fus_w[o * 384 + k];
  } else {
    int d = k - 256;
    float acc = 0.0f;
    for (int m = 0; m < 128; ++m)
      acc += fus_w[o * 384 + 256 + m] * dino_w[m * 384 + d];
    val = acc;
  }
  Wt4[((k >> 2) * 256 + o) * 4 + (k & 3)] = val;
}

// ---------------------------------------------------------------------------
// K2: pooled[b][o][cell] = (W @ sum_{16 px} x)/16 + bc.  Block = (b, i, jg of 4 cells).
__global__ __launch_bounds__(256) void k_fused_pool(
    const float* __restrict__ R, const float* __restrict__ F,
    const float* __restrict__ Wt4, const float* __restrict__ bc,
    float* __restrict__ pooled) {
  int blk = blockIdx.x;
  int b = blk >> 6;
  int i = (blk >> 2) & 15;
  int jg = blk & 3;
  int t = threadIdx.x;
  __shared__ float s[4 * 640];  // [cell][k]
  {  // R part: thread t = channel c, 4 rows x 4 cells of float4
    const float* rb = R + (((b * 256 + t) * 64 + i * 4) * 64) + jg * 16;
    float p0 = 0, p1 = 0, p2 = 0, p3 = 0;
#pragma unroll
    for (int di = 0; di < 4; ++di) {
      const float4* row = (const float4*)(rb + di * 64);
      float4 v0 = row[0], v1 = row[1], v2 = row[2], v3 = row[3];
      p0 += v0.x + v0.y + v0.z + v0.w;
      p1 += v1.x + v1.y + v1.z + v1.w;
      p2 += v2.x + v2.y + v2.z + v2.w;
      p3 += v3.x + v3.y + v3.z + v3.w;
    }
    s[0 * 640 + t] = p0;
    s[1 * 640 + t] = p1;
    s[2 * 640 + t] = p2;
    s[3 * 640 + t] = p3;
  }
  {  // F part: thread t covers k=t and k=t+256 (t<128)
    float a0[4] = {0, 0, 0, 0};
    float a1[4] = {0, 0, 0, 0};
    for (int pix = 0; pix < 16; ++pix) {
      int row = i * 4 + (pix >> 2);
      int pbase = row * 64 + jg * 16 + (pix & 3);
#pragma unroll
      for (int jj = 0; jj < 4; ++jj) {
        const float* fr = F + (size_t)(b * 4096 + pbase + jj * 4) * 384;
        a0[jj] += fr[t];
        if (t < 128) a1[jj] += fr[256 + t];
      }
    }
#pragma unroll
    for (int jj = 0; jj < 4; ++jj) {
      s[jj * 640 + 256 + t] = a0[jj];
      if (t < 128) s[jj * 640 + 512 + t] = a1[jj];
    }
  }
  __syncthreads();
  float acc0 = 0, acc1 = 0, acc2 = 0, acc3 = 0;
  const float4* w4 = (const float4*)Wt4;
  for (int kk = 0; kk < 160; ++kk) {
    float4 wv = w4[kk * 256 + t];
    float4 s0 = *(const float4*)&s[0 * 640 + kk * 4];
    float4 s1 = *(const float4*)&s[1 * 640 + kk * 4];
    float4 s2 = *(const float4*)&s[2 * 640 + kk * 4];
    float4 s3 = *(const float4*)&s[3 * 640 + kk * 4];
    acc0 += wv.x * s0.x + wv.y * s0.y + wv.z * s0.z + wv.w * s0.w;
    acc1 += wv.x * s1.x + wv.y * s1.y + wv.z * s1.z + wv.w * s1.w;
    acc2 += wv.x * s2.x + wv.y * s2.y + wv.z * s2.z + wv.w * s2.w;
    acc3 += wv.x * s3.x + wv.y * s3.y + wv.z * s3.z + wv.w * s3.w;
  }
  float bco = bc[t];
  float* pr = pooled + ((b * 256 + t) * 256) + i * 16 + jg * 4;
  pr[0] = acc0 * (1.0f / 16.0f) + bco;
  pr[1] = acc1 * (1.0f / 16.0f) + bco;
  pr[2] = acc2 * (1.0f / 16.0f) + bco;
  pr[3] = acc3 * (1.0f / 16.0f) + bco;
}

// ---------------------------------------------------------------------------
// K3a: f_gap = mean(pooled); h = relu(g1_w @ f_gap + g1_b). One block per b.
__global__ __launch_bounds__(256) void k_gap(
    const float* __restrict__ pooled, const float* __restrict__ g1_w,
    const float* __restrict__ g1_b, float* __restrict__ hout) {
  int b = blockIdx.x;
  int t = threadIdx.x;
  __shared__ float f[256];
  const float* pr = pooled + (b * 256 + t) * 256;
  float sum = 0.0f;
  for (int cell = 0; cell < 256; ++cell) sum += pr[cell];
  f[t] = sum * (1.0f / 256.0f);
  __syncthreads();
  float acc = g1_b[t];
  const float* wr = g1_w + t * 256;
  for (int k = 0; k < 256; ++k) acc += wr[k] * f[k];
  hout[b * 256 + t] = fmaxf(acc, 0.0f);
}

// ---------------------------------------------------------------------------
// K3b: G_global = h @ g2_w.T + g2_b  (+ slice-layout copy)
__global__ __launch_bounds__(256) void k_gglobal(
    const float* __restrict__ h, const float* __restrict__ g2_w,
    const float* __restrict__ g2_b, float* __restrict__ out3,
    float* __restrict__ rg) {
  int b = blockIdx.x / 24;
  int o = (blockIdx.x % 24) * 256 + threadIdx.x;
  __shared__ float hl[256];
  hl[threadIdx.x] = h[b * 256 + threadIdx.x];
  __syncthreads();
  float acc = g2_b[o];
  const float* wr = g2_w + o * 256;
  for (int k = 0; k < 256; ++k) acc += wr[k] * hl[k];
  out3[b * 6144 + o] = acc;
  int n = o >> 9, y = (o >> 6) & 7, x = (o >> 3) & 7, z = o & 7;
  rg[b * 6144 + ((y * 8 + x) * 8 + z) * 12 + n] = acc;
}

// ---------------------------------------------------------------------------
// K4: G_local = transpose(local_w @ pooled + local_b)  (+ slice-layout copy)
__global__ __launch_bounds__(256) void k_glocal(
    const float* __restrict__ pooled, const float* __restrict__ lw,
    const float* __restrict__ lb, float* __restrict__ out4,
    float* __restrict__ rl) {
  int idx = blockIdx.x * 256 + threadIdx.x;
  int b = idx / 24576;
  int r = idx - b * 24576;
  int o = r >> 8;
  int cell = r & 255;
  float acc = lb[o];
  const float* wr = lw + o * 256;
  const float* pr = pooled + b * 65536 + cell;
  for (int c = 0; c < 256; ++c) acc += wr[c] * pr[c * 256];
  int n = o >> 3, l = o & 7;
  out4[((b * 12 + n) * 256 + cell) * 8 + l] = acc;
  rl[b * 24576 + (cell * 8 + l) * 12 + n] = acc;
}

// ---------------------------------------------------------------------------
// K5: semantic guide. One wave handles 8 patches; lane = hidden unit.
// w1T[k][hidden] is read coalesced into 64 VGPRs per 64-wide k-chunk;
// F rows are wave-uniform float4 broadcast loads (1 line per load).
__global__ __launch_bounds__(256, 4) void k_guide(
    const float* __restrict__ F, const float* __restrict__ w1T,
    const float* __restrict__ b1, const float* __restrict__ w2,
    const float* __restrict__ b2, float* __restrict__ gsem) {
  int wave = threadIdx.x >> 6;
  int lane = threadIdx.x & 63;
  int gw = blockIdx.x * 4 + wave;   // 2048 waves
  int p0 = gw * 8;                  // first patch of this wave
  float acc[8];
#pragma unroll
  for (int p = 0; p < 8; ++p) acc[p] = 0.0f;
  const float* fbase = F + (size_t)p0 * 384;
  for (int c = 0; c < 6; ++c) {
    int k0 = c * 64;
    float wreg[64];
#pragma unroll
    for (int j = 0; j < 64; ++j) wreg[j] = w1T[(k0 + j) * 64 + lane];
#pragma unroll
    for (int p = 0; p < 8; ++p) {
      const float4* fr = (const float4*)(fbase + (size_t)p * 384 + k0);
#pragma unroll
      for (int q = 0; q < 16; ++q) {
        float4 v = fr[q];
        acc[p] += v.x * wreg[4 * q] + v.y * wreg[4 * q + 1] +
                  v.z * wreg[4 * q + 2] + v.w * wreg[4 * q + 3];
      }
    }
  }
  float hb = b1[lane];
  float wl = w2[lane];
  float b2v = b2[0];
  float res = 0.0f;
#pragma unroll
  for (int p = 0; p < 8; ++p) {
    float v = fmaxf(acc[p] + hb, 0.0f) * wl;
#pragma unroll
    for (int m = 32; m >= 1; m >>= 1) v += __shfl_xor(v, m, 64);
    if (lane == p) res = v;   // after butterfly, every lane has the sum
  }
  if (lane < 8) gsem[p0 + lane] = 1.0f / (1.0f + expf(-(res + b2v)));
}

// ---------------------------------------------------------------------------
// K6: per-pixel — Lab chroma, g_sem bilinear, g, two bilateral slices.
__device__ __forceinline__ void slice_apply(
    const float* __restrict__ gptr, int sdim, int h, int w, int z0, int z1,
    float wz, float r, float g, float bl, float& o0, float& o1, float& o2) {
  float sc = (float)(sdim - 1) * (1.0f / 895.0f);
  float fxs = (float)w * sc;
  float fys = (float)h * sc;
  int x0 = (int)fxs;
  if (x0 > sdim - 1) x0 = sdim - 1;
  int y0 = (int)fys;
  if (y0 > sdim - 1) y0 = sdim - 1;
  int x1 = x0 < sdim - 1 ? x0 + 1 : sdim - 1;
  int y1 = y0 < sdim - 1 ? y0 + 1 : sdim - 1;
  float wx = fxs - (float)x0;
  float wy = fys - (float)y0;
  float w00 = (1.0f - wy) * (1.0f - wx);
  float w01 = (1.0f - wy) * wx;
  float w10 = wy * (1.0f - wx);
  float w11 = wy * wx;
  float wz0 = 1.0f - wz;
  int dz = (z1 - z0) * 12;
  float a[12];
#pragma unroll
  for (int c = 0; c < 12; ++c) a[c] = 0.0f;
#pragma unroll
  for (int corner = 0; corner < 4; ++corner) {
    int cy = (corner & 2) ? y1 : y0;
    int cx = (corner & 1) ? x1 : x0;
    float wyx = (corner == 0) ? w00 : (corner == 1) ? w01 : (corner == 2) ? w10 : w11;
    const float* p = gptr + ((cy * sdim + cx) * 8 + z0) * 12;
    float wA = wyx * wz0, wB = wyx * wz;
#pragma unroll
    for (int c = 0; c < 12; c += 4) {
      float4 v0 = *(const float4*)(p + c);
      float4 v1 = *(const float4*)(p + dz + c);
      a[c + 0] += wA * v0.x + wB * v1.x;
      a[c + 1] += wA * v0.y + wB * v1.y;
      a[c + 2] += wA * v0.z + wB * v1.z;
      a[c + 3] += wA * v0.w + wB * v1.w;
    }
  }
  o0 = fminf(fmaxf(a[0] * r + a[1] * g + a[2] * bl + a[9], 0.0f), 1.0f);
  o1 = fminf(fmaxf(a[3] * r + a[4] * g + a[5] * bl + a[10], 0.0f), 1.0f);
  o2 = fminf(fmaxf(a[6] * r + a[7] * g + a[8] * bl + a[11], 0.0f), 1.0f);
}

__global__ __launch_bounds__(256) void k_pixel(
    const float* __restrict__ img, const float* __restrict__ gsem,
    const float* __restrict__ rg, const float* __restrict__ rl,
    float* __restrict__ out) {
  int pix = blockIdx.x * 256 + threadIdx.x;
  int b = pix / HWPIX;
  int hw = pix - b * HWPIX;
  int h = hw / 896;
  int w = hw - h * 896;
  float r = img[(b * 3 + 0) * HWPIX + hw];
  float g = img[(b * 3 + 1) * HWPIX + hw];
  float bl = img[(b * 3 + 2) * HWPIX + hw];
  // Lab -> chroma guide
  float lr = srgb_lin(r), lg = srgb_lin(g), lb2 = srgb_lin(bl);
  float X = 0.412453f * lr + 0.357580f * lg + 0.180423f * lb2;
  float Y = 0.212671f * lr + 0.715160f * lg + 0.072169f * lb2;
  float Z = 0.019334f * lr + 0.119193f * lg + 0.950227f * lb2;
  float fx_ = labf(X * (1.0f / 0.950456f));
  float fy_ = labf(Y);
  float fz_ = labf(Z * (1.0f / 1.088754f));
  float L = 116.0f * fy_ - 16.0f;
  float Aa = 500.0f * (fx_ - fy_);
  float Bb = 200.0f * (fy_ - fz_);
  float gch = (0.5f * L + 0.25f * fabsf(Aa) + 0.25f * fabsf(Bb)) * (1.0f / 114.0f);
  gch = fminf(fmaxf(gch, 0.0f), 1.0f);
  // g_sem bilinear upsample (half-pixel centers, edge clamp)
  float sy = fminf(fmaxf((h + 0.5f) * (1.0f / 14.0f) - 0.5f, 0.0f), 63.0f);
  float sx = fminf(fmaxf((w + 0.5f) * (1.0f / 14.0f) - 0.5f, 0.0f), 63.0f);
  int y0 = (int)sy;
  int x0 = (int)sx;
  int y1 = y0 < 63 ? y0 + 1 : 63;
  int x1 = x0 < 63 ? x0 + 1 : 63;
  float wy = sy - (float)y0;
  float wx = sx - (float)x0;
  const float* gb = gsem + b * 4096;
  float g00 = gb[y0 * 64 + x0], g01 = gb[y0 * 64 + x1];
  float g10 = gb[y1 * 64 + x0], g11 = gb[y1 * 64 + x1];
  float gs = (g00 * (1.0f - wx) + g01 * wx) * (1.0f - wy) +
             (g10 * (1.0f - wx) + g11 * wx) * wy;
  float gg = 0.5f * gch + 0.5f * gs;
  out[OUT_G + pix] = gg;
  // z coordinate shared by both slices (l=8 for both)
  float fzc = fminf(fmaxf(gg * 7.0f, 0.0f), 7.0f);
  int z0 = (int)fzc;
  if (z0 > 7) z0 = 7;
  int z1 = z0 < 7 ? z0 + 1 : 7;
  float wz = fzc - (float)z0;
  float o0, o1, o2;
  slice_apply(rg + b * 6144, 8, h, w, z0, z1, wz, r, g, bl, o0, o1, o2);
  out[(b * 3 + 0) * HWPIX + hw] = o0;
  out[(b * 3 + 1) * HWPIX + hw] = o1;
  out[(b * 3 + 2) * HWPIX + hw] = o2;
  slice_apply(rl + b * 24576, 16, h, w, z0, z1, wz, r, g, bl, o0, o1, o2);
  out[OUT_IL + (b * 3 + 0) * HWPIX + hw] = o0;
  out[OUT_IL + (b * 3 + 1) * HWPIX + hw] = o1;
  out[OUT_IL + (b * 3 + 2) * HWPIX + hw] = o2;
}

// ---------------------------------------------------------------------------
extern "C" void kernel_launch(void* const* d_in, const int* in_sizes, int n_in,
                              void* d_out, int out_size, void* d_ws,
                              size_t ws_size, hipStream_t stream) {
  const float* R = (const float*)d_in[0];
  const float* F = (const float*)d_in[1];
  const float* img = (const float*)d_in[2];
  const float* dino_w = (const float*)d_in[5];
  const float* dino_b = (const float*)d_in[6];
  const float* fus_w = (const float*)d_in[7];
  const float* fus_b = (const float*)d_in[8];
  const float* g1_w = (const float*)d_in[9];
  const float* g1_b = (const float*)d_in[10];
  const float* g2_w = (const float*)d_in[11];
  const float* g2_b = (const float*)d_in[12];
  const float* lw = (const float*)d_in[13];
  const float* lb = (const float*)d_in[14];
  const float* gw1 = (const float*)d_in[15];
  const float* gb1 = (const float*)d_in[16];
  const float* gw2 = (const float*)d_in[17];
  const float* gb2 = (const float*)d_in[18];
  float* out = (float*)d_out;
  float* ws = (float*)d_ws;

  float* Wt4 = ws + WS_WT4;
  float* bc = ws + WS_BC;
  float* pooled = ws + WS_POOL;
  float* hbuf = ws + WS_H;
  float* gsem = ws + WS_GSEM;
  float* rg = ws + WS_RG;
  float* rl = ws + WS_RL;
  float* w1T = ws + WS_W1T;

  k_prep<<<642, 256, 0, stream>>>(fus_w, fus_b, dino_w, dino_b, gw1, Wt4, bc, w1T);
  k_guide<<<512, 256, 0, stream>>>(F, w1T, gb1, gw2, gb2, gsem);
  k_fused_pool<<<256, 256, 0, stream>>>(R, F, Wt4, bc, pooled);
  k_gap<<<4, 256, 0, stream>>>(pooled, g1_w, g1_b, hbuf);
  k_gglobal<<<96, 256, 0, stream>>>(hbuf, g2_w, g2_b, out + OUT_GG, rg);
  k_glocal<<<384, 256, 0, stream>>>(pooled, lw, lb, out + OUT_GL, rl);
  k_pixel<<<12544, 256, 0, stream>>>(img, gsem, rg, rl, out);
}

// Round 3
// 435.647 us; speedup vs baseline: 1.6816x; 1.6816x over previous
//
#include <hip/hip_runtime.h>
#include <math.h>

// Problem constants (fixed by setup_inputs): B=4, H=W=896, n_h=n_w=64,
// GS=8, GL=8, LS=16, LL=8, NA=12, ALPHA=0.5
#define HWPIX 802816            // 896*896
#define OUT_IL 9633792          // offset of I_local  (4*3*896*896)
#define OUT_GG 19267584         // offset of G_global
#define OUT_GL 19292160         // offset of G_local
#define OUT_G  19390464         // offset of g

// workspace layout (float offsets)
#define WS_WT4  0               // combined weight, packed [k/4][o][4], 256x640
#define WS_BC   163840          // combined bias, 256
#define WS_POOL 164096          // pooled [b][c][cell], 4*256*256
#define WS_H    426240          // h vector, 4*256
#define WS_GSEM 427264          // g_sem_patch, 4*4096
#define WS_RG   443648          // global grid [b][y][x][z][c], 4*8*8*8*12
#define WS_RL   468224          // local grid  [b][y][x][z][c], 4*16*16*8*12
#define WS_W1T  566528          // guide_w1 packed [k/4][hidden][4], 384*64

__device__ __forceinline__ float srgb_lin(float v) {
  return v > 0.04045f ? __powf((v + 0.055f) * (1.0f / 1.055f), 2.4f)
                      : v * (1.0f / 12.92f);
}
__device__ __forceinline__ float labf(float t) {
  return t > 0.008856f ? cbrtf(t) : 7.787f * t + (4.0f / 29.0f);
}

// ---------------------------------------------------------------------------
// K1: combined weight W[o][k] (k<256: fusion Wa; k>=256: Wb @ dino_proj_w)
// packed as Wt4[(k>>2)*256 + o][k&3]; plus bc[o] = fusion_b + Wb @ dino_b.
// block 641 packs guide_w1 -> w1T4[((k>>2)*64 + h)*4 + (k&3)].
__global__ __launch_bounds__(256) void k_prep(
    const float* __restrict__ fus_w, const float* __restrict__ fus_b,
    const float* __restrict__ dino_w, const float* __restrict__ dino_b,
    const float* __restrict__ gw1, float* __restrict__ Wt4,
    float* __restrict__ bc, float* __restrict__ w1T) {
  if (blockIdx.x == 641) {
    int t = threadIdx.x;
    for (int it = 0; it < 96; ++it) {
      int idx = it * 256 + t;       // idx over 384*64; k = idx>>6, h = idx&63
      int h = idx & 63;
      int k = idx >> 6;
      w1T[((k >> 2) * 64 + h) * 4 + (k & 3)] = gw1[h * 384 + k];
    }
    return;
  }
  if (blockIdx.x == 640) {
    int o = threadIdx.x;
    float acc = fus_b[o];
    for (int m = 0; m < 128; ++m) acc += fus_w[o * 384 + 256 + m] * dino_b[m];
    bc[o] = acc;
    return;
  }
  int idx = blockIdx.x * 256 + threadIdx.x;
  int o = idx / 640;
  int k = idx - o * 640;
  float val;
  if (k < 256) {
    val = fus_w[o * 384 + k];
  } else {
    int d = k - 256;
    float acc = 0.0f;
    for (int m = 0; m < 128; ++m)
      acc += fus_w[o * 384 + 256 + m] * dino_w[m * 384 + d];
    val = acc;
  }
  Wt4[((k >> 2) * 256 + o) * 4 + (k & 3)] = val;
}

// ---------------------------------------------------------------------------
// K2: pooled[b][o][cell] = (W @ sum_{16 px} x)/16 + bc.  Block = (b, i, jg of 4 cells).
__global__ __launch_bounds__(256) void k_fused_pool(
    const float* __restrict__ R, const float* __restrict__ F,
    const float* __restrict__ Wt4, const float* __restrict__ bc,
    float* __restrict__ pooled) {
  int blk = blockIdx.x;
  int b = blk >> 6;
  int i = (blk >> 2) & 15;
  int jg = blk & 3;
  int t = threadIdx.x;
  __shared__ float s[4 * 640];  // [cell][k]
  {  // R part: thread t = channel c, 4 rows x 4 cells of float4
    const float* rb = R + (((b * 256 + t) * 64 + i * 4) * 64) + jg * 16;
    float p0 = 0, p1 = 0, p2 = 0, p3 = 0;
#pragma unroll
    for (int di = 0; di < 4; ++di) {
      const float4* row = (const float4*)(rb + di * 64);
      float4 v0 = row[0], v1 = row[1], v2 = row[2], v3 = row[3];
      p0 += v0.x + v0.y + v0.z + v0.w;
      p1 += v1.x + v1.y + v1.z + v1.w;
      p2 += v2.x + v2.y + v2.z + v2.w;
      p3 += v3.x + v3.y + v3.z + v3.w;
    }
    s[0 * 640 + t] = p0;
    s[1 * 640 + t] = p1;
    s[2 * 640 + t] = p2;
    s[3 * 640 + t] = p3;
  }
  {  // F part: thread t covers k=t and k=t+256 (t<128)
    float a0[4] = {0, 0, 0, 0};
    float a1[4] = {0, 0, 0, 0};
    for (int pix = 0; pix < 16; ++pix) {
      int row = i * 4 + (pix >> 2);
      int pbase = row * 64 + jg * 16 + (pix & 3);
#pragma unroll
      for (int jj = 0; jj < 4; ++jj) {
        const float* fr = F + (size_t)(b * 4096 + pbase + jj * 4) * 384;
        a0[jj] += fr[t];
        if (t < 128) a1[jj] += fr[256 + t];
      }
    }
#pragma unroll
    for (int jj = 0; jj < 4; ++jj) {
      s[jj * 640 + 256 + t] = a0[jj];
      if (t < 128) s[jj * 640 + 512 + t] = a1[jj];
    }
  }
  __syncthreads();
  float acc0 = 0, acc1 = 0, acc2 = 0, acc3 = 0;
  const float4* w4 = (const float4*)Wt4;
  for (int kk = 0; kk < 160; ++kk) {
    float4 wv = w4[kk * 256 + t];
    float4 s0 = *(const float4*)&s[0 * 640 + kk * 4];
    float4 s1 = *(const float4*)&s[1 * 640 + kk * 4];
    float4 s2 = *(const float4*)&s[2 * 640 + kk * 4];
    float4 s3 = *(const float4*)&s[3 * 640 + kk * 4];
    acc0 += wv.x * s0.x + wv.y * s0.y + wv.z * s0.z + wv.w * s0.w;
    acc1 += wv.x * s1.x + wv.y * s1.y + wv.z * s1.z + wv.w * s1.w;
    acc2 += wv.x * s2.x + wv.y * s2.y + wv.z * s2.z + wv.w * s2.w;
    acc3 += wv.x * s3.x + wv.y * s3.y + wv.z * s3.z + wv.w * s3.w;
  }
  float bco = bc[t];
  float* pr = pooled + ((b * 256 + t) * 256) + i * 16 + jg * 4;
  pr[0] = acc0 * (1.0f / 16.0f) + bco;
  pr[1] = acc1 * (1.0f / 16.0f) + bco;
  pr[2] = acc2 * (1.0f / 16.0f) + bco;
  pr[3] = acc3 * (1.0f / 16.0f) + bco;
}

// ---------------------------------------------------------------------------
// K3a: f_gap = mean(pooled); h = relu(g1_w @ f_gap + g1_b). One block per b.
__global__ __launch_bounds__(256) void k_gap(
    const float* __restrict__ pooled, const float* __restrict__ g1_w,
    const float* __restrict__ g1_b, float* __restrict__ hout) {
  int b = blockIdx.x;
  int t = threadIdx.x;
  __shared__ float f[256];
  const float* pr = pooled + (b * 256 + t) * 256;
  float sum = 0.0f;
  for (int cell = 0; cell < 256; ++cell) sum += pr[cell];
  f[t] = sum * (1.0f / 256.0f);
  __syncthreads();
  float acc = g1_b[t];
  const float* wr = g1_w + t * 256;
  for (int k = 0; k < 256; ++k) acc += wr[k] * f[k];
  hout[b * 256 + t] = fmaxf(acc, 0.0f);
}

// ---------------------------------------------------------------------------
// K3b: G_global = h @ g2_w.T + g2_b  (+ slice-layout copy)
__global__ __launch_bounds__(256) void k_gglobal(
    const float* __restrict__ h, const float* __restrict__ g2_w,
    const float* __restrict__ g2_b, float* __restrict__ out3,
    float* __restrict__ rg) {
  int b = blockIdx.x / 24;
  int o = (blockIdx.x % 24) * 256 + threadIdx.x;
  __shared__ float hl[256];
  hl[threadIdx.x] = h[b * 256 + threadIdx.x];
  __syncthreads();
  float acc = g2_b[o];
  const float* wr = g2_w + o * 256;
  for (int k = 0; k < 256; ++k) acc += wr[k] * hl[k];
  out3[b * 6144 + o] = acc;
  int n = o >> 9, y = (o >> 6) & 7, x = (o >> 3) & 7, z = o & 7;
  rg[b * 6144 + ((y * 8 + x) * 8 + z) * 12 + n] = acc;
}

// ---------------------------------------------------------------------------
// K4: G_local = transpose(local_w @ pooled + local_b)  (+ slice-layout copy)
__global__ __launch_bounds__(256) void k_glocal(
    const float* __restrict__ pooled, const float* __restrict__ lw,
    const float* __restrict__ lb, float* __restrict__ out4,
    float* __restrict__ rl) {
  int idx = blockIdx.x * 256 + threadIdx.x;
  int b = idx / 24576;
  int r = idx - b * 24576;
  int o = r >> 8;
  int cell = r & 255;
  float acc = lb[o];
  const float* wr = lw + o * 256;
  const float* pr = pooled + b * 65536 + cell;
  for (int c = 0; c < 256; ++c) acc += wr[c] * pr[c * 256];
  int n = o >> 3, l = o & 7;
  out4[((b * 12 + n) * 256 + cell) * 8 + l] = acc;
  rl[b * 24576 + (cell * 8 + l) * 12 + n] = acc;
}

// ---------------------------------------------------------------------------
// K5: semantic guide. One wave = 8 patches; lane = hidden unit.
// w1T packed [k/4][h][4]: each lane reads its 4 k-values as one float4
// (coalesced, 16B/lane). F rows are wave-uniform float4 broadcast loads.
// K walked in chunks of 8 -> register working set stays ~40 VGPRs (the
// round-2 wreg[64] variant spilled to scratch: 900 MB HBM traffic).
__global__ __launch_bounds__(256) void k_guide(
    const float* __restrict__ F, const float* __restrict__ w1T,
    const float* __restrict__ b1, const float* __restrict__ w2,
    const float* __restrict__ b2, float* __restrict__ gsem) {
  int wave = threadIdx.x >> 6;
  int lane = threadIdx.x & 63;
  int gw = blockIdx.x * 4 + wave;   // 2048 waves
  int p0 = gw * 8;                  // first patch of this wave
  float acc[8];
#pragma unroll
  for (int p = 0; p < 8; ++p) acc[p] = 0.0f;
  const float* fbase = F + (size_t)p0 * 384;
  const float4* w4 = (const float4*)w1T;   // [k/4][64 lanes]
  for (int c = 0; c < 48; ++c) {           // 8 k per chunk
    int k0 = c * 8;
    float4 wa = w4[(c * 2 + 0) * 64 + lane];  // k0..k0+3
    float4 wb = w4[(c * 2 + 1) * 64 + lane];  // k0+4..k0+7
#pragma unroll
    for (int p = 0; p < 8; ++p) {
      const float4* fr = (const float4*)(fbase + (size_t)p * 384 + k0);
      float4 va = fr[0];
      float4 vb = fr[1];
      acc[p] += va.x * wa.x + va.y * wa.y + va.z * wa.z + va.w * wa.w +
                vb.x * wb.x + vb.y * wb.y + vb.z * wb.z + vb.w * wb.w;
    }
  }
  float hb = b1[lane];
  float wl = w2[lane];
  float b2v = b2[0];
  float res = 0.0f;
#pragma unroll
  for (int p = 0; p < 8; ++p) {
    float v = fmaxf(acc[p] + hb, 0.0f) * wl;
#pragma unroll
    for (int m = 32; m >= 1; m >>= 1) v += __shfl_xor(v, m, 64);
    if (lane == p) res = v;   // after butterfly, every lane has the sum
  }
  if (lane < 8) gsem[p0 + lane] = 1.0f / (1.0f + expf(-(res + b2v)));
}

// ---------------------------------------------------------------------------
// K6: per-pixel — Lab chroma, g_sem bilinear, g, two bilateral slices.
__device__ __forceinline__ void slice_apply(
    const float* __restrict__ gptr, int sdim, int h, int w, int z0, int z1,
    float wz, float r, float g, float bl, float& o0, float& o1, float& o2) {
  float sc = (float)(sdim - 1) * (1.0f / 895.0f);
  float fxs = (float)w * sc;
  float fys = (float)h * sc;
  int x0 = (int)fxs;
  if (x0 > sdim - 1) x0 = sdim - 1;
  int y0 = (int)fys;
  if (y0 > sdim - 1) y0 = sdim - 1;
  int x1 = x0 < sdim - 1 ? x0 + 1 : sdim - 1;
  int y1 = y0 < sdim - 1 ? y0 + 1 : sdim - 1;
  float wx = fxs - (float)x0;
  float wy = fys - (float)y0;
  float w00 = (1.0f - wy) * (1.0f - wx);
  float w01 = (1.0f - wy) * wx;
  float w10 = wy * (1.0f - wx);
  float w11 = wy * wx;
  float wz0 = 1.0f - wz;
  int dz = (z1 - z0) * 12;
  float a[12];
#pragma unroll
  for (int c = 0; c < 12; ++c) a[c] = 0.0f;
#pragma unroll
  for (int corner = 0; corner < 4; ++corner) {
    int cy = (corner & 2) ? y1 : y0;
    int cx = (corner & 1) ? x1 : x0;
    float wyx = (corner == 0) ? w00 : (corner == 1) ? w01 : (corner == 2) ? w10 : w11;
    const float* p = gptr + ((cy * sdim + cx) * 8 + z0) * 12;
    float wA = wyx * wz0, wB = wyx * wz;
#pragma unroll
    for (int c = 0; c < 12; c += 4) {
      float4 v0 = *(const float4*)(p + c);
      float4 v1 = *(const float4*)(p + dz + c);
      a[c + 0] += wA * v0.x + wB * v1.x;
      a[c + 1] += wA * v0.y + wB * v1.y;
      a[c + 2] += wA * v0.z + wB * v1.z;
      a[c + 3] += wA * v0.w + wB * v1.w;
    }
  }
  o0 = fminf(fmaxf(a[0] * r + a[1] * g + a[2] * bl + a[9], 0.0f), 1.0f);
  o1 = fminf(fmaxf(a[3] * r + a[4] * g + a[5] * bl + a[10], 0.0f), 1.0f);
  o2 = fminf(fmaxf(a[6] * r + a[7] * g + a[8] * bl + a[11], 0.0f), 1.0f);
}

__global__ __launch_bounds__(256) void k_pixel(
    const float* __restrict__ img, const float* __restrict__ gsem,
    const float* __restrict__ rg, const float* __restrict__ rl,
    float* __restrict__ out) {
  int pix = blockIdx.x * 256 + threadIdx.x;
  int b = pix / HWPIX;
  int hw = pix - b * HWPIX;
  int h = hw / 896;
  int w = hw - h * 896;
  float r = img[(b * 3 + 0) * HWPIX + hw];
  float g = img[(b * 3 + 1) * HWPIX + hw];
  float bl = img[(b * 3 + 2) * HWPIX + hw];
  // Lab -> chroma guide
  float lr = srgb_lin(r), lg = srgb_lin(g), lb2 = srgb_lin(bl);
  float X = 0.412453f * lr + 0.357580f * lg + 0.180423f * lb2;
  float Y = 0.212671f * lr + 0.715160f * lg + 0.072169f * lb2;
  float Z = 0.019334f * lr + 0.119193f * lg + 0.950227f * lb2;
  float fx_ = labf(X * (1.0f / 0.950456f));
  float fy_ = labf(Y);
  float fz_ = labf(Z * (1.0f / 1.088754f));
  float L = 116.0f * fy_ - 16.0f;
  float Aa = 500.0f * (fx_ - fy_);
  float Bb = 200.0f * (fy_ - fz_);
  float gch = (0.5f * L + 0.25f * fabsf(Aa) + 0.25f * fabsf(Bb)) * (1.0f / 114.0f);
  gch = fminf(fmaxf(gch, 0.0f), 1.0f);
  // g_sem bilinear upsample (half-pixel centers, edge clamp)
  float sy = fminf(fmaxf((h + 0.5f) * (1.0f / 14.0f) - 0.5f, 0.0f), 63.0f);
  float sx = fminf(fmaxf((w + 0.5f) * (1.0f / 14.0f) - 0.5f, 0.0f), 63.0f);
  int y0 = (int)sy;
  int x0 = (int)sx;
  int y1 = y0 < 63 ? y0 + 1 : 63;
  int x1 = x0 < 63 ? x0 + 1 : 63;
  float wy = sy - (float)y0;
  float wx = sx - (float)x0;
  const float* gb = gsem + b * 4096;
  float g00 = gb[y0 * 64 + x0], g01 = gb[y0 * 64 + x1];
  float g10 = gb[y1 * 64 + x0], g11 = gb[y1 * 64 + x1];
  float gs = (g00 * (1.0f - wx) + g01 * wx) * (1.0f - wy) +
             (g10 * (1.0f - wx) + g11 * wx) * wy;
  float gg = 0.5f * gch + 0.5f * gs;
  out[OUT_G + pix] = gg;
  // z coordinate shared by both slices (l=8 for both)
  float fzc = fminf(fmaxf(gg * 7.0f, 0.0f), 7.0f);
  int z0 = (int)fzc;
  if (z0 > 7) z0 = 7;
  int z1 = z0 < 7 ? z0 + 1 : 7;
  float wz = fzc - (float)z0;
  float o0, o1, o2;
  slice_apply(rg + b * 6144, 8, h, w, z0, z1, wz, r, g, bl, o0, o1, o2);
  out[(b * 3 + 0) * HWPIX + hw] = o0;
  out[(b * 3 + 1) * HWPIX + hw] = o1;
  out[(b * 3 + 2) * HWPIX + hw] = o2;
  slice_apply(rl + b * 24576, 16, h, w, z0, z1, wz, r, g, bl, o0, o1, o2);
  out[OUT_IL + (b * 3 + 0) * HWPIX + hw] = o0;
  out[OUT_IL + (b * 3 + 1) * HWPIX + hw] = o1;
  out[OUT_IL + (b * 3 + 2) * HWPIX + hw] = o2;
}

// ---------------------------------------------------------------------------
extern "C" void kernel_launch(void* const* d_in, const int* in_sizes, int n_in,
                              void* d_out, int out_size, void* d_ws,
                              size_t ws_size, hipStream_t stream) {
  const float* R = (const float*)d_in[0];
  const float* F = (const float*)d_in[1];
  const float* img = (const float*)d_in[2];
  const float* dino_w = (const float*)d_in[5];
  const float* dino_b = (const float*)d_in[6];
  const float* fus_w = (const float*)d_in[7];
  const float* fus_b = (const float*)d_in[8];
  const float* g1_w = (const float*)d_in[9];
  const float* g1_b = (const float*)d_in[10];
  const float* g2_w = (const float*)d_in[11];
  const float* g2_b = (const float*)d_in[12];
  const float* lw = (const float*)d_in[13];
  const float* lb = (const float*)d_in[14];
  const float* gw1 = (const float*)d_in[15];
  const float* gb1 = (const float*)d_in[16];
  const float* gw2 = (const float*)d_in[17];
  const float* gb2 = (const float*)d_in[18];
  float* out = (float*)d_out;
  float* ws = (float*)d_ws;

  float* Wt4 = ws + WS_WT4;
  float* bc = ws + WS_BC;
  float* pooled = ws + WS_POOL;
  float* hbuf = ws + WS_H;
  float* gsem = ws + WS_GSEM;
  float* rg = ws + WS_RG;
  float* rl = ws + WS_RL;
  float* w1T = ws + WS_W1T;

  k_prep<<<642, 256, 0, stream>>>(fus_w, fus_b, dino_w, dino_b, gw1, Wt4, bc, w1T);
  k_guide<<<512, 256, 0, stream>>>(F, w1T, gb1, gw2, gb2, gsem);
  k_fused_pool<<<256, 256, 0, stream>>>(R, F, Wt4, bc, pooled);
  k_gap<<<4, 256, 0, stream>>>(pooled, g1_w, g1_b, hbuf);
  k_gglobal<<<96, 256, 0, stream>>>(hbuf, g2_w, g2_b, out + OUT_GG, rg);
  k_glocal<<<384, 256, 0, stream>>>(pooled, lw, lb, out + OUT_GL, rl);
  k_pixel<<<12544, 256, 0, stream>>>(img, gsem, rg, rl, out);
}

// Round 5
// 432.699 us; speedup vs baseline: 1.6930x; 1.0068x over previous
//
#include <hip/hip_runtime.h>
#include <math.h>

// Problem constants (fixed by setup_inputs): B=4, H=W=896, n_h=n_w=64,
// GS=8, GL=8, LS=16, LL=8, NA=12, ALPHA=0.5
#define HWPIX 802816            // 896*896
#define OUT_IL 9633792          // offset of I_local  (4*3*896*896)
#define OUT_GG 19267584         // offset of G_global
#define OUT_GL 19292160         // offset of G_local
#define OUT_G  19390464         // offset of g

// workspace layout (float offsets)
#define WS_WT4  0               // combined weight, packed [k/4][o][4], 256x640
#define WS_BC   163840          // combined bias, 256
#define WS_POOL 164096          // pooled [b][c][cell], 4*256*256
#define WS_H    426240          // h vector, 4*256
#define WS_GSEM 427264          // g_sem_patch, 4*4096
#define WS_RG   443648          // global grid [b][y][x][z][c], 4*8*8*8*12
#define WS_RL   468224          // local grid  [b][y][x][z][c], 4*16*16*8*12
#define WS_W1T  566528          // guide_w1 packed [k/4][hidden][4], 384*64

// Fast transcendentals: v_log_f32 (log2 semantics) / v_exp_f32 (exp2) via
// the clang AMDGPU builtins — the CUDA-style __exp2f/__log2f names collide
// with glibc math.h under hipcc (round-4 compile failure). The libm
// cbrtf/powf expansions were the round-3 VALU hog.
__device__ __forceinline__ float fast_exp2(float x) {
  return __builtin_amdgcn_exp2f(x);
}
__device__ __forceinline__ float fast_log2(float x) {
  return __builtin_amdgcn_logf(x);  // v_log_f32 = log2(x)
}
__device__ __forceinline__ float srgb_lin(float v) {
  // pow path only selected for v > 0.04045 (argument strictly positive)
  float p = fast_exp2(2.4f * fast_log2((v + 0.055f) * (1.0f / 1.055f)));
  return v > 0.04045f ? p : v * (1.0f / 12.92f);
}
__device__ __forceinline__ float labf(float t) {
  // cbrt path only selected for t > 0.008856; log2(0)=-inf -> exp2 -> 0 is
  // discarded by the select, no NaN (t >= 0 always here).
  float c = fast_exp2((1.0f / 3.0f) * fast_log2(t));
  return t > 0.008856f ? c : 7.787f * t + (4.0f / 29.0f);
}

// ---------------------------------------------------------------------------
// K1: combined weight W[o][k] (k<256: fusion Wa; k>=256: Wb @ dino_proj_w)
// packed as Wt4[(k>>2)*256 + o][k&3]; plus bc[o] = fusion_b + Wb @ dino_b.
// block 641 packs guide_w1 -> w1T4[((k>>2)*64 + h)*4 + (k&3)].
__global__ __launch_bounds__(256) void k_prep(
    const float* __restrict__ fus_w, const float* __restrict__ fus_b,
    const float* __restrict__ dino_w, const float* __restrict__ dino_b,
    const float* __restrict__ gw1, float* __restrict__ Wt4,
    float* __restrict__ bc, float* __restrict__ w1T) {
  if (blockIdx.x == 641) {
    int t = threadIdx.x;
    for (int it = 0; it < 96; ++it) {
      int idx = it * 256 + t;       // idx over 384*64; k = idx>>6, h = idx&63
      int h = idx & 63;
      int k = idx >> 6;
      w1T[((k >> 2) * 64 + h) * 4 + (k & 3)] = gw1[h * 384 + k];
    }
    return;
  }
  if (blockIdx.x == 640) {
    int o = threadIdx.x;
    float acc = fus_b[o];
    for (int m = 0; m < 128; ++m) acc += fus_w[o * 384 + 256 + m] * dino_b[m];
    bc[o] = acc;
    return;
  }
  int idx = blockIdx.x * 256 + threadIdx.x;
  int o = idx / 640;
  int k = idx - o * 640;
  float val;
  if (k < 256) {
    val = fus_w[o * 384 + k];
  } else {
    int d = k - 256;
    float acc = 0.0f;
    for (int m = 0; m < 128; ++m)
      acc += fus_w[o * 384 + 256 + m] * dino_w[m * 384 + d];
    val = acc;
  }
  Wt4[((k >> 2) * 256 + o) * 4 + (k & 3)] = val;
}

// ---------------------------------------------------------------------------
// K2: pooled[b][o][cell] = (W @ sum_{16 px} x)/16 + bc.  Block = (b, i, jg of 4 cells).
__global__ __launch_bounds__(256) void k_fused_pool(
    const float* __restrict__ R, const float* __restrict__ F,
    const float* __restrict__ Wt4, const float* __restrict__ bc,
    float* __restrict__ pooled) {
  int blk = blockIdx.x;
  int b = blk >> 6;
  int i = (blk >> 2) & 15;
  int jg = blk & 3;
  int t = threadIdx.x;
  __shared__ float s[4 * 640];  // [cell][k]
  {  // R part: thread t = channel c, 4 rows x 4 cells of float4
    const float* rb = R + (((b * 256 + t) * 64 + i * 4) * 64) + jg * 16;
    float p0 = 0, p1 = 0, p2 = 0, p3 = 0;
#pragma unroll
    for (int di = 0; di < 4; ++di) {
      const float4* row = (const float4*)(rb + di * 64);
      float4 v0 = row[0], v1 = row[1], v2 = row[2], v3 = row[3];
      p0 += v0.x + v0.y + v0.z + v0.w;
      p1 += v1.x + v1.y + v1.z + v1.w;
      p2 += v2.x + v2.y + v2.z + v2.w;
      p3 += v3.x + v3.y + v3.z + v3.w;
    }
    s[0 * 640 + t] = p0;
    s[1 * 640 + t] = p1;
    s[2 * 640 + t] = p2;
    s[3 * 640 + t] = p3;
  }
  {  // F part: thread t covers k=t and k=t+256 (t<128)
    float a0[4] = {0, 0, 0, 0};
    float a1[4] = {0, 0, 0, 0};
    for (int pix = 0; pix < 16; ++pix) {
      int row = i * 4 + (pix >> 2);
      int pbase = row * 64 + jg * 16 + (pix & 3);
#pragma unroll
      for (int jj = 0; jj < 4; ++jj) {
        const float* fr = F + (size_t)(b * 4096 + pbase + jj * 4) * 384;
        a0[jj] += fr[t];
        if (t < 128) a1[jj] += fr[256 + t];
      }
    }
#pragma unroll
    for (int jj = 0; jj < 4; ++jj) {
      s[jj * 640 + 256 + t] = a0[jj];
      if (t < 128) s[jj * 640 + 512 + t] = a1[jj];
    }
  }
  __syncthreads();
  float acc0 = 0, acc1 = 0, acc2 = 0, acc3 = 0;
  const float4* w4 = (const float4*)Wt4;
  for (int kk = 0; kk < 160; ++kk) {
    float4 wv = w4[kk * 256 + t];
    float4 s0 = *(const float4*)&s[0 * 640 + kk * 4];
    float4 s1 = *(const float4*)&s[1 * 640 + kk * 4];
    float4 s2 = *(const float4*)&s[2 * 640 + kk * 4];
    float4 s3 = *(const float4*)&s[3 * 640 + kk * 4];
    acc0 += wv.x * s0.x + wv.y * s0.y + wv.z * s0.z + wv.w * s0.w;
    acc1 += wv.x * s1.x + wv.y * s1.y + wv.z * s1.z + wv.w * s1.w;
    acc2 += wv.x * s2.x + wv.y * s2.y + wv.z * s2.z + wv.w * s2.w;
    acc3 += wv.x * s3.x + wv.y * s3.y + wv.z * s3.z + wv.w * s3.w;
  }
  float bco = bc[t];
  float* pr = pooled + ((b * 256 + t) * 256) + i * 16 + jg * 4;
  pr[0] = acc0 * (1.0f / 16.0f) + bco;
  pr[1] = acc1 * (1.0f / 16.0f) + bco;
  pr[2] = acc2 * (1.0f / 16.0f) + bco;
  pr[3] = acc3 * (1.0f / 16.0f) + bco;
}

// ---------------------------------------------------------------------------
// K3a: f_gap = mean(pooled); h = relu(g1_w @ f_gap + g1_b). One block per b.
__global__ __launch_bounds__(256) void k_gap(
    const float* __restrict__ pooled, const float* __restrict__ g1_w,
    const float* __restrict__ g1_b, float* __restrict__ hout) {
  int b = blockIdx.x;
  int t = threadIdx.x;
  __shared__ float f[256];
  const float* pr = pooled + (b * 256 + t) * 256;
  float sum = 0.0f;
  for (int cell = 0; cell < 256; ++cell) sum += pr[cell];
  f[t] = sum * (1.0f / 256.0f);
  __syncthreads();
  float acc = g1_b[t];
  const float* wr = g1_w + t * 256;
  for (int k = 0; k < 256; ++k) acc += wr[k] * f[k];
  hout[b * 256 + t] = fmaxf(acc, 0.0f);
}

// ---------------------------------------------------------------------------
// K3b: G_global = h @ g2_w.T + g2_b  (+ slice-layout copy)
__global__ __launch_bounds__(256) void k_gglobal(
    const float* __restrict__ h, const float* __restrict__ g2_w,
    const float* __restrict__ g2_b, float* __restrict__ out3,
    float* __restrict__ rg) {
  int b = blockIdx.x / 24;
  int o = (blockIdx.x % 24) * 256 + threadIdx.x;
  __shared__ float hl[256];
  hl[threadIdx.x] = h[b * 256 + threadIdx.x];
  __syncthreads();
  float acc = g2_b[o];
  const float* wr = g2_w + o * 256;
  for (int k = 0; k < 256; ++k) acc += wr[k] * hl[k];
  out3[b * 6144 + o] = acc;
  int n = o >> 9, y = (o >> 6) & 7, x = (o >> 3) & 7, z = o & 7;
  rg[b * 6144 + ((y * 8 + x) * 8 + z) * 12 + n] = acc;
}

// ---------------------------------------------------------------------------
// K4: G_local = transpose(local_w @ pooled + local_b)  (+ slice-layout copy)
__global__ __launch_bounds__(256) void k_glocal(
    const float* __restrict__ pooled, const float* __restrict__ lw,
    const float* __restrict__ lb, float* __restrict__ out4,
    float* __restrict__ rl) {
  int idx = blockIdx.x * 256 + threadIdx.x;
  int b = idx / 24576;
  int r = idx - b * 24576;
  int o = r >> 8;
  int cell = r & 255;
  float acc = lb[o];
  const float* wr = lw + o * 256;
  const float* pr = pooled + b * 65536 + cell;
  for (int c = 0; c < 256; ++c) acc += wr[c] * pr[c * 256];
  int n = o >> 3, l = o & 7;
  out4[((b * 12 + n) * 256 + cell) * 8 + l] = acc;
  rl[b * 24576 + (cell * 8 + l) * 12 + n] = acc;
}

// ---------------------------------------------------------------------------
// K5: semantic guide. One wave = 8 patches; lane = hidden unit.
// w1T packed [k/4][h][4]: each lane reads its 4 k-values as one float4
// (coalesced, 16B/lane). F rows are wave-uniform float4 broadcast loads.
// K walked in chunks of 8 -> register working set stays ~40 VGPRs (the
// round-2 wreg[64] variant spilled to scratch: 900 MB HBM traffic).
__global__ __launch_bounds__(256) void k_guide(
    const float* __restrict__ F, const float* __restrict__ w1T,
    const float* __restrict__ b1, const float* __restrict__ w2,
    const float* __restrict__ b2, float* __restrict__ gsem) {
  int wave = threadIdx.x >> 6;
  int lane = threadIdx.x & 63;
  int gw = blockIdx.x * 4 + wave;   // 2048 waves
  int p0 = gw * 8;                  // first patch of this wave
  float acc[8];
#pragma unroll
  for (int p = 0; p < 8; ++p) acc[p] = 0.0f;
  const float* fbase = F + (size_t)p0 * 384;
  const float4* w4 = (const float4*)w1T;   // [k/4][64 lanes]
  for (int c = 0; c < 48; ++c) {           // 8 k per chunk
    int k0 = c * 8;
    float4 wa = w4[(c * 2 + 0) * 64 + lane];  // k0..k0+3
    float4 wb = w4[(c * 2 + 1) * 64 + lane];  // k0+4..k0+7
#pragma unroll
    for (int p = 0; p < 8; ++p) {
      const float4* fr = (const float4*)(fbase + (size_t)p * 384 + k0);
      float4 va = fr[0];
      float4 vb = fr[1];
      acc[p] += va.x * wa.x + va.y * wa.y + va.z * wa.z + va.w * wa.w +
                vb.x * wb.x + vb.y * wb.y + vb.z * wb.z + vb.w * wb.w;
    }
  }
  float hb = b1[lane];
  float wl = w2[lane];
  float b2v = b2[0];
  float res = 0.0f;
#pragma unroll
  for (int p = 0; p < 8; ++p) {
    float v = fmaxf(acc[p] + hb, 0.0f) * wl;
#pragma unroll
    for (int m = 32; m >= 1; m >>= 1) v += __shfl_xor(v, m, 64);
    if (lane == p) res = v;   // after butterfly, every lane has the sum
  }
  if (lane < 8) gsem[p0 + lane] = 1.0f / (1.0f + expf(-(res + b2v)));
}

// ---------------------------------------------------------------------------
// K6: per-pixel — Lab chroma, g_sem bilinear, g, two bilateral slices.
// SDIM is compile-time so the scale constants and clamps fold.
template <int SDIM>
__device__ __forceinline__ void slice_apply(
    const float* __restrict__ gptr, int h, int w, int z0, int z1,
    float wz, float r, float g, float bl, float& o0, float& o1, float& o2) {
  constexpr float sc = (float)(SDIM - 1) * (1.0f / 895.0f);
  float fxs = (float)w * sc;
  float fys = (float)h * sc;
  int x0 = (int)fxs;
  if (x0 > SDIM - 1) x0 = SDIM - 1;
  int y0 = (int)fys;
  if (y0 > SDIM - 1) y0 = SDIM - 1;
  int x1 = x0 < SDIM - 1 ? x0 + 1 : SDIM - 1;
  int y1 = y0 < SDIM - 1 ? y0 + 1 : SDIM - 1;
  float wx = fxs - (float)x0;
  float wy = fys - (float)y0;
  float w00 = (1.0f - wy) * (1.0f - wx);
  float w01 = (1.0f - wy) * wx;
  float w10 = wy * (1.0f - wx);
  float w11 = wy * wx;
  float wz0 = 1.0f - wz;
  int dz = (z1 - z0) * 12;
  float a[12];
#pragma unroll
  for (int c = 0; c < 12; ++c) a[c] = 0.0f;
#pragma unroll
  for (int corner = 0; corner < 4; ++corner) {
    int cy = (corner & 2) ? y1 : y0;
    int cx = (corner & 1) ? x1 : x0;
    float wyx = (corner == 0) ? w00 : (corner == 1) ? w01 : (corner == 2) ? w10 : w11;
    const float* p = gptr + ((cy * SDIM + cx) * 8 + z0) * 12;
    float wA = wyx * wz0, wB = wyx * wz;
#pragma unroll
    for (int c = 0; c < 12; c += 4) {
      float4 v0 = *(const float4*)(p + c);
      float4 v1 = *(const float4*)(p + dz + c);
      a[c + 0] += wA * v0.x + wB * v1.x;
      a[c + 1] += wA * v0.y + wB * v1.y;
      a[c + 2] += wA * v0.z + wB * v1.z;
      a[c + 3] += wA * v0.w + wB * v1.w;
    }
  }
  o0 = fminf(fmaxf(a[0] * r + a[1] * g + a[2] * bl + a[9], 0.0f), 1.0f);
  o1 = fminf(fmaxf(a[3] * r + a[4] * g + a[5] * bl + a[10], 0.0f), 1.0f);
  o2 = fminf(fmaxf(a[6] * r + a[7] * g + a[8] * bl + a[11], 0.0f), 1.0f);
}

__global__ __launch_bounds__(256) void k_pixel(
    const float* __restrict__ img, const float* __restrict__ gsem,
    const float* __restrict__ rg, const float* __restrict__ rl,
    float* __restrict__ out) {
  int pix = blockIdx.x * 256 + threadIdx.x;
  int b = pix / HWPIX;
  int hw = pix - b * HWPIX;
  int h = hw / 896;
  int w = hw - h * 896;
  float r = img[(b * 3 + 0) * HWPIX + hw];
  float g = img[(b * 3 + 1) * HWPIX + hw];
  float bl = img[(b * 3 + 2) * HWPIX + hw];
  // Lab -> chroma guide (constants folded: (0.5*116 fy - 0.5*16 +
  // 0.25*500|fx-fy| + 0.25*200|fy-fz|)/114)
  float lr = srgb_lin(r), lg = srgb_lin(g), lb2 = srgb_lin(bl);
  float X = 0.412453f * lr + 0.357580f * lg + 0.180423f * lb2;
  float Y = 0.212671f * lr + 0.715160f * lg + 0.072169f * lb2;
  float Z = 0.019334f * lr + 0.119193f * lg + 0.950227f * lb2;
  float fx_ = labf(X * (1.0f / 0.950456f));
  float fy_ = labf(Y);
  float fz_ = labf(Z * (1.0f / 1.088754f));
  float gch = 0.50877193f * fy_ - 0.070175439f +
              1.0964912f * fabsf(fx_ - fy_) + 0.43859649f * fabsf(fy_ - fz_);
  gch = fminf(fmaxf(gch, 0.0f), 1.0f);
  // g_sem bilinear upsample (half-pixel centers, edge clamp)
  float sy = fminf(fmaxf((h + 0.5f) * (1.0f / 14.0f) - 0.5f, 0.0f), 63.0f);
  float sx = fminf(fmaxf((w + 0.5f) * (1.0f / 14.0f) - 0.5f, 0.0f), 63.0f);
  int y0 = (int)sy;
  int x0 = (int)sx;
  int y1 = y0 < 63 ? y0 + 1 : 63;
  int x1 = x0 < 63 ? x0 + 1 : 63;
  float wy = sy - (float)y0;
  float wx = sx - (float)x0;
  const float* gb = gsem + b * 4096;
  float g00 = gb[y0 * 64 + x0], g01 = gb[y0 * 64 + x1];
  float g10 = gb[y1 * 64 + x0], g11 = gb[y1 * 64 + x1];
  float gs = (g00 * (1.0f - wx) + g01 * wx) * (1.0f - wy) +
             (g10 * (1.0f - wx) + g11 * wx) * wy;
  float gg = 0.5f * gch + 0.5f * gs;
  __builtin_nontemporal_store(gg, &out[OUT_G + pix]);
  // z coordinate shared by both slices (l=8 for both)
  float fzc = fminf(fmaxf(gg * 7.0f, 0.0f), 7.0f);
  int z0 = (int)fzc;
  if (z0 > 7) z0 = 7;
  int z1 = z0 < 7 ? z0 + 1 : 7;
  float wz = fzc - (float)z0;
  float o0, o1, o2;
  slice_apply<8>(rg + b * 6144, h, w, z0, z1, wz, r, g, bl, o0, o1, o2);
  __builtin_nontemporal_store(o0, &out[(b * 3 + 0) * HWPIX + hw]);
  __builtin_nontemporal_store(o1, &out[(b * 3 + 1) * HWPIX + hw]);
  __builtin_nontemporal_store(o2, &out[(b * 3 + 2) * HWPIX + hw]);
  slice_apply<16>(rl + b * 24576, h, w, z0, z1, wz, r, g, bl, o0, o1, o2);
  __builtin_nontemporal_store(o0, &out[OUT_IL + (b * 3 + 0) * HWPIX + hw]);
  __builtin_nontemporal_store(o1, &out[OUT_IL + (b * 3 + 1) * HWPIX + hw]);
  __builtin_nontemporal_store(o2, &out[OUT_IL + (b * 3 + 2) * HWPIX + hw]);
}

// ---------------------------------------------------------------------------
extern "C" void kernel_launch(void* const* d_in, const int* in_sizes, int n_in,
                              void* d_out, int out_size, void* d_ws,
                              size_t ws_size, hipStream_t stream) {
  const float* R = (const float*)d_in[0];
  const float* F = (const float*)d_in[1];
  const float* img = (const float*)d_in[2];
  const float* dino_w = (const float*)d_in[5];
  const float* dino_b = (const float*)d_in[6];
  const float* fus_w = (const float*)d_in[7];
  const float* fus_b = (const float*)d_in[8];
  const float* g1_w = (const float*)d_in[9];
  const float* g1_b = (const float*)d_in[10];
  const float* g2_w = (const float*)d_in[11];
  const float* g2_b = (const float*)d_in[12];
  const float* lw = (const float*)d_in[13];
  const float* lb = (const float*)d_in[14];
  const float* gw1 = (const float*)d_in[15];
  const float* gb1 = (const float*)d_in[16];
  const float* gw2 = (const float*)d_in[17];
  const float* gb2 = (const float*)d_in[18];
  float* out = (float*)d_out;
  float* ws = (float*)d_ws;

  float* Wt4 = ws + WS_WT4;
  float* bc = ws + WS_BC;
  float* pooled = ws + WS_POOL;
  float* hbuf = ws + WS_H;
  float* gsem = ws + WS_GSEM;
  float* rg = ws + WS_RG;
  float* rl = ws + WS_RL;
  float* w1T = ws + WS_W1T;

  k_prep<<<642, 256, 0, stream>>>(fus_w, fus_b, dino_w, dino_b, gw1, Wt4, bc, w1T);
  k_guide<<<512, 256, 0, stream>>>(F, w1T, gb1, gw2, gb2, gsem);
  k_fused_pool<<<256, 256, 0, stream>>>(R, F, Wt4, bc, pooled);
  k_gap<<<4, 256, 0, stream>>>(pooled, g1_w, g1_b, hbuf);
  k_gglobal<<<96, 256, 0, stream>>>(hbuf, g2_w, g2_b, out + OUT_GG, rg);
  k_glocal<<<384, 256, 0, stream>>>(pooled, lw, lb, out + OUT_GL, rl);
  k_pixel<<<12544, 256, 0, stream>>>(img, gsem, rg, rl, out);
}